// Round 6
// baseline (133.772 us; speedup 1.0000x reference)
//
#include <hip/hip_runtime.h>
#include <hip/hip_bf16.h>
#include <math.h>

// Shapes: L=2048, B=32, E=1, S=4, D=8, N=8, P=720
#define LEN 2048
#define BDIM 32
#define PDIM 720
#define LROWS 8              // l-rows per block in kernel A

// Device-global scratch (NOT d_ws; harness never touches these).
// Both arrays fully rewritten by kernel A every call before kernel B reads
// them => no cross-call state, re-poison-safe. 16B-aligned for float4 loads.
__device__ __attribute__((aligned(16))) float g_u[LEN];
__device__ __attribute__((aligned(16))) float g_hh[LEN];

__device__ __forceinline__ float sigmoidf_(float x) { return 1.0f / (1.0f + expf(-x)); }
__device__ __forceinline__ float siluf_(float x)    { return x / (1.0f + expf(-x)); }

// ============ Kernel A: fused precompute + attention row-sum ================
// E=1 collapse: xn == norm_b[0] (constant c). Per l:
//   mx(l)   = silu(c*sum_n (g_n/om_n)(1-q_n^{l+1}) + c*omega)   [closed-form conv]
//   q8(l)   = [ (z*ag0+ab0)/L , rot_a(l) ],  Kv(m) = [ z*ag1+ab1 , rot_b(m) ]
//   A(l)    = sum_m relu(q8(l).Kv(m))^2
//   hh(l)   = silu(hx + A*wsum + bh0),  u(l) = sigmoid(base0)
// Grid: 256 blocks x 256 thr; each block serves l = blockIdx*8 .. +7 and
// redundantly recomputes ALL Kv rows into LDS (transposed, conflict-free).
__global__ void kA_rowsum(
    const float* __restrict__ norm_b,
    const float* __restrict__ ema_delta, const float* __restrict__ ema_alpha,
    const float* __restrict__ ema_beta,  const float* __restrict__ ema_gamma,
    const float* __restrict__ ema_omega,
    const float* __restrict__ Wv, const float* __restrict__ bv,
    const float* __restrict__ Wmx, const float* __restrict__ bmx,
    const float* __restrict__ Wh, const float* __restrict__ bh,
    const float* __restrict__ attn_gamma, const float* __restrict__ attn_beta,
    const float* __restrict__ rot_alpha,  const float* __restrict__ rot_beta)
{
    __shared__ float kv[8][LEN];          // 64 KB: kv[d][m], transposed
    __shared__ float qs[LROWS][8];
    __shared__ float hxs[LROWS], wss[LROWS];
    __shared__ float red[4][LROWS];

    const int tid   = threadIdx.x;
    const int wave  = tid >> 6;
    const int lane  = tid & 63;
    const int lbase = blockIdx.x * LROWS;

    const float c     = norm_b[0];
    const float res_e = c * ema_omega[0];
    const float f1    = expf(-logf(10000.0f) * 0.5f);   // rotary freq[1]

    // hoisted per-n EMA constants (l-independent)
    float gon[8], lq[8];
    #pragma unroll
    for (int n = 0; n < 8; ++n) {
        float p  = sigmoidf_(ema_delta[n]);
        float s  = sigmoidf_(ema_alpha[n]);
        float om = p * s;                 // 1-q in (0,1)
        gon[n] = p * ema_beta[n] * ema_gamma[n] * 0.35355339059327373f / om;
        lq[n]  = logf(1.0f - om);
    }

    // ---- Phase 0a: build all Kv rows (thread t -> m = t + k*256) ----
    #pragma unroll
    for (int k = 0; k < 8; ++k) {
        const int m = tid + (k << 8);
        float conv = 0.0f;
        #pragma unroll
        for (int n = 0; n < 8; ++n)
            conv += gon[n] * (1.0f - expf((float)(m + 1) * lq[n]));
        const float mx = siluf_(conv * c + res_e);

        #pragma unroll
        for (int s = 0; s < 4; ++s) {
            float z = siluf_(fmaf(mx, Wmx[1 + s], bmx[1 + s]));
            kv[s][m] = fmaf(z, attn_gamma[4 + s], attn_beta[4 + s]);
        }
        const float mf = (float)m;
        const float c0 = cosf(mf),      s0 = sinf(mf);
        const float th = mf * f1;
        const float c1 = cosf(th),      s1 = sinf(th);
        kv[4][m] = rot_beta[0] * c0 - rot_beta[2] * s0;
        kv[5][m] = rot_beta[1] * c1 - rot_beta[3] * s1;
        kv[6][m] = rot_beta[2] * c0 + rot_beta[0] * s0;
        kv[7][m] = rot_beta[3] * c1 + rot_beta[1] * s1;
    }

    // ---- Phase 0b: own-l q8 / u / hx / wsum (threads 0..7) ----
    if (tid < LROWS) {
        const int l = lbase + tid;
        float conv = 0.0f;
        #pragma unroll
        for (int n = 0; n < 8; ++n)
            conv += gon[n] * (1.0f - expf((float)(l + 1) * lq[n]));
        const float mx = siluf_(conv * c + res_e);

        g_u[l] = sigmoidf_(fmaf(mx, Wmx[0], bmx[0]));

        const float invL = 1.0f / (float)LEN;
        #pragma unroll
        for (int s = 0; s < 4; ++s) {
            float z = siluf_(fmaf(mx, Wmx[1 + s], bmx[1 + s]));
            qs[tid][s] = fmaf(z, attn_gamma[s], attn_beta[s]) * invL;
        }
        const float lf = (float)l;
        const float c0 = cosf(lf),      s0 = sinf(lf);
        const float th = lf * f1;
        const float c1 = cosf(th),      s1 = sinf(th);
        qs[tid][4] = rot_alpha[0] * c0 - rot_alpha[2] * s0;
        qs[tid][5] = rot_alpha[1] * c1 - rot_alpha[3] * s1;
        qs[tid][6] = rot_alpha[2] * c0 + rot_alpha[0] * s0;
        qs[tid][7] = rot_alpha[3] * c1 + rot_alpha[1] * s1;

        hxs[tid] = fmaf(mx, Wmx[13], bmx[13]);
        float ws = 0.0f;
        #pragma unroll
        for (int d = 0; d < 8; ++d) {
            float r = siluf_(fmaf(mx, Wmx[5 + d], bmx[5 + d]));
            float v = siluf_(fmaf(c, Wv[d], bv[d]));
            ws += v * r * Wh[d];
        }
        wss[tid] = ws;
    }
    __syncthreads();

    // ---- Phase 1: dot products (8 l-rows x 2048 m, m = tid + k*256) ----
    float q[LROWS][8];
    #pragma unroll
    for (int r = 0; r < LROWS; ++r)
        #pragma unroll
        for (int d = 0; d < 8; ++d) q[r][d] = qs[r][d];   // broadcast reads

    float acc[LROWS] = {0, 0, 0, 0, 0, 0, 0, 0};
    #pragma unroll
    for (int k = 0; k < 8; ++k) {
        const int m = tid + (k << 8);
        float kd[8];
        #pragma unroll
        for (int d = 0; d < 8; ++d) kd[d] = kv[d][m];     // conflict-free b32
        #pragma unroll
        for (int r = 0; r < LROWS; ++r) {
            float dot = q[r][0] * kd[0] + q[r][1] * kd[1] + q[r][2] * kd[2]
                      + q[r][3] * kd[3] + q[r][4] * kd[4] + q[r][5] * kd[5]
                      + q[r][6] * kd[6] + q[r][7] * kd[7];
            dot = fmaxf(dot, 0.0f);
            acc[r] = fmaf(dot, dot, acc[r]);
        }
    }

    // ---- Phase 2: block reduction -> hh ----
    #pragma unroll
    for (int r = 0; r < LROWS; ++r) {
        #pragma unroll
        for (int off = 32; off; off >>= 1)
            acc[r] += __shfl_down(acc[r], off, 64);
    }
    if (lane == 0) {
        #pragma unroll
        for (int r = 0; r < LROWS; ++r) red[wave][r] = acc[r];
    }
    __syncthreads();
    if (tid < LROWS) {
        float A = red[0][tid] + red[1][tid] + red[2][tid] + red[3][tid];
        g_hh[lbase + tid] = siluf_(hxs[tid] + A * wss[tid] + bh[0]);
    }
}

// ============ Kernel B: fused gate + output projection ======================
// y[b,p] = blin[p] + sum_l (x[b,l] + u[l]*(hh[l]-x[b,l])) * Wlin[p,l]
// One block per p; wave w handles batches 8w..8w+7; 8 chunk-iters of batched
// float4 loads (unroll 2 for memory-level parallelism).
__global__ void kB_output(
    const float* __restrict__ x,
    const float* __restrict__ Wlin, const float* __restrict__ blin,
    float* __restrict__ y)
{
    const int p     = blockIdx.x;
    const int tid   = threadIdx.x;
    const int wave  = tid >> 6;
    const int lane  = tid & 63;
    const int bbase = wave * 8;

    const float4* W4 = (const float4*)(Wlin + (size_t)p * LEN);
    const float4* U4 = (const float4*)g_u;
    const float4* H4 = (const float4*)g_hh;

    float acc[8] = {0, 0, 0, 0, 0, 0, 0, 0};

    #pragma unroll 2
    for (int k = 0; k < 8; ++k) {
        const int i4 = (k << 6) + lane;           // float4 index along l
        const float4 wv = W4[i4];
        const float4 uv = U4[i4];
        const float4 hv = H4[i4];
        float4 xv[8];
        #pragma unroll
        for (int j = 0; j < 8; ++j)
            xv[j] = ((const float4*)(x + (size_t)(bbase + j) * LEN))[i4];

        #pragma unroll
        for (int j = 0; j < 8; ++j) {
            float ox = fmaf(uv.x, hv.x - xv[j].x, xv[j].x);
            float oy = fmaf(uv.y, hv.y - xv[j].y, xv[j].y);
            float oz = fmaf(uv.z, hv.z - xv[j].z, xv[j].z);
            float ow = fmaf(uv.w, hv.w - xv[j].w, xv[j].w);
            acc[j] += fmaf(ox, wv.x, fmaf(oy, wv.y, fmaf(oz, wv.z, ow * wv.w)));
        }
    }

    #pragma unroll
    for (int j = 0; j < 8; ++j) {
        float v = acc[j];
        #pragma unroll
        for (int off = 32; off; off >>= 1) v += __shfl_down(v, off, 64);
        if (lane == 0)
            y[(size_t)(bbase + j) * PDIM + p] = v + blin[p];
    }
}

// ---------------- launch ----------------------------------------------------
extern "C" void kernel_launch(void* const* d_in, const int* in_sizes, int n_in,
                              void* d_out, int out_size, void* d_ws, size_t ws_size,
                              hipStream_t stream)
{
    const float* x          = (const float*)d_in[0];
    // d_in[1] = norm_w (dead: multiplies exact zero since E=1)
    const float* norm_b     = (const float*)d_in[2];
    const float* ema_delta  = (const float*)d_in[3];
    const float* ema_alpha  = (const float*)d_in[4];
    const float* ema_beta   = (const float*)d_in[5];
    const float* ema_gamma  = (const float*)d_in[6];
    const float* ema_omega  = (const float*)d_in[7];
    const float* Wv         = (const float*)d_in[8];
    const float* bv         = (const float*)d_in[9];
    const float* Wmx        = (const float*)d_in[10];
    const float* bmx        = (const float*)d_in[11];
    const float* Wh         = (const float*)d_in[12];
    const float* bh         = (const float*)d_in[13];
    const float* attn_gamma = (const float*)d_in[14];
    const float* attn_beta  = (const float*)d_in[15];
    const float* rot_alpha  = (const float*)d_in[16];
    const float* rot_beta   = (const float*)d_in[17];
    const float* Wlin       = (const float*)d_in[18];
    const float* blin       = (const float*)d_in[19];
    float* y = (float*)d_out;

    kA_rowsum<<<LEN / LROWS, 256, 0, stream>>>(
        norm_b, ema_delta, ema_alpha, ema_beta, ema_gamma, ema_omega,
        Wv, bv, Wmx, bmx, Wh, bh, attn_gamma, attn_beta, rot_alpha, rot_beta);

    kB_output<<<PDIM, 256, 0, stream>>>(x, Wlin, blin, y);
}

// Round 7
// 121.262 us; speedup vs baseline: 1.1032x; 1.1032x over previous
//
#include <hip/hip_runtime.h>
#include <hip/hip_bf16.h>
#include <math.h>

// Shapes: L=2048, B=32, E=1, S=4, D=8, N=8, P=720
#define LEN 2048
#define BDIM 32
#define PDIM 720

// Device-global scratch (NOT d_ws; harness never touches these). Every region
// fully overwritten each call before any read (k1 writes Qv/Kv/u/hx/wsum; k2
// writes hh) => no cross-call state, re-poison-safe. 16B-aligned for float4.
__device__ __attribute__((aligned(16))) float g_Qv[LEN * 8];
__device__ __attribute__((aligned(16))) float g_Kv[LEN * 8];
__device__ __attribute__((aligned(16))) float g_u[LEN];
__device__ __attribute__((aligned(16))) float g_hx[LEN];
__device__ __attribute__((aligned(16))) float g_wsum[LEN];
__device__ __attribute__((aligned(16))) float g_hh[LEN];

__device__ __forceinline__ float sigmoidf_(float x) { return 1.0f / (1.0f + expf(-x)); }
__device__ __forceinline__ float siluf_(float x)    { return x / (1.0f + expf(-x)); }

// ---------------- K1: per-position precompute (E=1 collapse) ----------------
// Proven in R3/R5. xn == norm_b[0] (constant c); FFT long-conv replaced by
// closed-form geometric prefix.
__global__ void k1_precompute(
    const float* __restrict__ norm_b,
    const float* __restrict__ ema_delta, const float* __restrict__ ema_alpha,
    const float* __restrict__ ema_beta,  const float* __restrict__ ema_gamma,
    const float* __restrict__ ema_omega,
    const float* __restrict__ Wv, const float* __restrict__ bv,
    const float* __restrict__ Wmx, const float* __restrict__ bmx,
    const float* __restrict__ Wh,
    const float* __restrict__ attn_gamma, const float* __restrict__ attn_beta,
    const float* __restrict__ rot_alpha,  const float* __restrict__ rot_beta)
{
    const int l = blockIdx.x * blockDim.x + threadIdx.x;
    if (l >= LEN) return;

    const float c = norm_b[0];
    const float res_e = c * ema_omega[0];

    float conv = 0.0f;
    #pragma unroll
    for (int n = 0; n < 8; ++n) {
        float p  = sigmoidf_(ema_delta[n]);
        float s  = sigmoidf_(ema_alpha[n]);
        float om = p * s;            // 1-q in (0,1)
        float q  = 1.0f - om;
        float g  = p * ema_beta[n] * ema_gamma[n] * 0.35355339059327373f; // 1/sqrt(8)
        float qp = expf((float)(l + 1) * logf(q));
        conv += g * (1.0f - qp) / om;
    }
    conv *= c;

    const float mx = siluf_(conv + res_e);

    const float u  = sigmoidf_(fmaf(mx, Wmx[0], bmx[0]));
    float z[4];
    #pragma unroll
    for (int s = 0; s < 4; ++s) z[s] = siluf_(fmaf(mx, Wmx[1 + s], bmx[1 + s]));
    float r[8];
    #pragma unroll
    for (int d = 0; d < 8; ++d) r[d] = siluf_(fmaf(mx, Wmx[5 + d], bmx[5 + d]));
    const float hx = fmaf(mx, Wmx[13], bmx[13]);

    float ws = 0.0f;
    #pragma unroll
    for (int d = 0; d < 8; ++d) {
        float v = siluf_(fmaf(c, Wv[d], bv[d]));
        ws += v * r[d] * Wh[d];
    }

    // rotary: half=2, freq={1, exp(-log(1e4)/2)}
    const float f1 = expf(-logf(10000.0f) * 0.5f);
    const float c0 = cosf((float)l),      s0 = sinf((float)l);
    const float th = (float)l * f1;
    const float c1 = cosf(th),            s1 = sinf(th);

    const float ra0 = rot_alpha[0] * c0 - rot_alpha[2] * s0;
    const float ra1 = rot_alpha[1] * c1 - rot_alpha[3] * s1;
    const float ra2 = rot_alpha[2] * c0 + rot_alpha[0] * s0;
    const float ra3 = rot_alpha[3] * c1 + rot_alpha[1] * s1;
    const float rb0 = rot_beta[0] * c0 - rot_beta[2] * s0;
    const float rb1 = rot_beta[1] * c1 - rot_beta[3] * s1;
    const float rb2 = rot_beta[2] * c0 + rot_beta[0] * s0;
    const float rb3 = rot_beta[3] * c1 + rot_beta[1] * s1;

    const float invL = 1.0f / (float)LEN;
    float* q8 = g_Qv + l * 8;
    float* k8 = g_Kv + l * 8;
    #pragma unroll
    for (int s = 0; s < 4; ++s) {
        q8[s] = fmaf(z[s], attn_gamma[s],     attn_beta[s])     * invL;
        k8[s] = fmaf(z[s], attn_gamma[4 + s], attn_beta[4 + s]);
    }
    q8[4] = ra0; q8[5] = ra1; q8[6] = ra2; q8[7] = ra3;
    k8[4] = rb0; k8[5] = rb1; k8[6] = rb2; k8[7] = rb3;

    g_u[l] = u; g_hx[l] = hx; g_wsum[l] = ws;
}

// ---------------- K2: attention row-sum A[l] -> hh[l] -----------------------
// Proven in R3/R5. A[l] = sum_m relu(Qv[l].Kv[m])^2; hh = silu(hx + A*wsum + bh0)
__global__ void k2_rowsum(const float* __restrict__ bh)
{
    const int l = blockIdx.x;
    const int tid = threadIdx.x;

    const float* q8 = g_Qv + l * 8;
    const float q0 = q8[0], q1 = q8[1], q2 = q8[2], q3 = q8[3];
    const float q4 = q8[4], q5 = q8[5], q6 = q8[6], q7 = q8[7];

    const float4* K4 = (const float4*)g_Kv;
    float acc = 0.0f;
    #pragma unroll
    for (int k = 0; k < LEN / 256; ++k) {
        int m = tid + k * 256;
        float4 ka = K4[m * 2];
        float4 kb = K4[m * 2 + 1];
        float d = q0 * ka.x + q1 * ka.y + q2 * ka.z + q3 * ka.w
                + q4 * kb.x + q5 * kb.y + q6 * kb.z + q7 * kb.w;
        d = fmaxf(d, 0.0f);
        acc = fmaf(d, d, acc);
    }
    #pragma unroll
    for (int off = 32; off; off >>= 1) acc += __shfl_down(acc, off, 64);

    __shared__ float red[4];
    if ((tid & 63) == 0) red[tid >> 6] = acc;
    __syncthreads();
    if (tid == 0) {
        float A = red[0] + red[1] + red[2] + red[3];
        g_hh[l] = siluf_(g_hx[l] + A * g_wsum[l] + bh[0]);
    }
}

// ---------------- KB: fused gate + output projection, 2 p-rows/block --------
// y[b,p] = blin[p] + sum_l (x[b,l] + u[l]*(hh[l]-x[b,l])) * Wlin[p,l]
// 360 blocks x 512 thr. Block owns p0=2*blk, p0+1 (halves x re-read traffic:
// 184 -> 92 MB L2). Wave w (of 8) handles batches 4w..4w+3; lanes stride l
// as float4; 7 batched loads per iter before one waitcnt; gate computed once,
// accumulated into both p dot-products.
__global__ void kB_output(
    const float* __restrict__ x,
    const float* __restrict__ Wlin, const float* __restrict__ blin,
    float* __restrict__ y)
{
    const int p0    = blockIdx.x * 2;
    const int tid   = threadIdx.x;
    const int wave  = tid >> 6;          // 0..7
    const int lane  = tid & 63;
    const int bbase = wave * 4;

    const float4* W0 = (const float4*)(Wlin + (size_t)p0 * LEN);
    const float4* W1 = (const float4*)(Wlin + (size_t)(p0 + 1) * LEN);
    const float4* U4 = (const float4*)g_u;
    const float4* H4 = (const float4*)g_hh;

    float acc0[4] = {0, 0, 0, 0};
    float acc1[4] = {0, 0, 0, 0};

    #pragma unroll 2
    for (int k = 0; k < 8; ++k) {
        const int i4 = (k << 6) + lane;   // float4 index along l
        const float4 w0 = W0[i4];
        const float4 w1 = W1[i4];
        const float4 uv = U4[i4];
        const float4 hv = H4[i4];
        float4 xv[4];
        #pragma unroll
        for (int j = 0; j < 4; ++j)
            xv[j] = ((const float4*)(x + (size_t)(bbase + j) * LEN))[i4];

        #pragma unroll
        for (int j = 0; j < 4; ++j) {
            float ox = fmaf(uv.x, hv.x - xv[j].x, xv[j].x);
            float oy = fmaf(uv.y, hv.y - xv[j].y, xv[j].y);
            float oz = fmaf(uv.z, hv.z - xv[j].z, xv[j].z);
            float ow = fmaf(uv.w, hv.w - xv[j].w, xv[j].w);
            acc0[j] += fmaf(ox, w0.x, fmaf(oy, w0.y, fmaf(oz, w0.z, ow * w0.w)));
            acc1[j] += fmaf(ox, w1.x, fmaf(oy, w1.y, fmaf(oz, w1.z, ow * w1.w)));
        }
    }

    #pragma unroll
    for (int j = 0; j < 4; ++j) {
        float v0 = acc0[j], v1 = acc1[j];
        #pragma unroll
        for (int off = 32; off; off >>= 1) {
            v0 += __shfl_down(v0, off, 64);
            v1 += __shfl_down(v1, off, 64);
        }
        if (lane == 0) {
            const size_t row = (size_t)(bbase + j) * PDIM;
            y[row + p0]     = v0 + blin[p0];
            y[row + p0 + 1] = v1 + blin[p0 + 1];
        }
    }
}

// ---------------- launch ----------------------------------------------------
extern "C" void kernel_launch(void* const* d_in, const int* in_sizes, int n_in,
                              void* d_out, int out_size, void* d_ws, size_t ws_size,
                              hipStream_t stream)
{
    const float* x          = (const float*)d_in[0];
    // d_in[1] = norm_w (dead: multiplies exact zero since E=1)
    const float* norm_b     = (const float*)d_in[2];
    const float* ema_delta  = (const float*)d_in[3];
    const float* ema_alpha  = (const float*)d_in[4];
    const float* ema_beta   = (const float*)d_in[5];
    const float* ema_gamma  = (const float*)d_in[6];
    const float* ema_omega  = (const float*)d_in[7];
    const float* Wv         = (const float*)d_in[8];
    const float* bv         = (const float*)d_in[9];
    const float* Wmx        = (const float*)d_in[10];
    const float* bmx        = (const float*)d_in[11];
    const float* Wh         = (const float*)d_in[12];
    const float* bh         = (const float*)d_in[13];
    const float* attn_gamma = (const float*)d_in[14];
    const float* attn_beta  = (const float*)d_in[15];
    const float* rot_alpha  = (const float*)d_in[16];
    const float* rot_beta   = (const float*)d_in[17];
    const float* Wlin       = (const float*)d_in[18];
    const float* blin       = (const float*)d_in[19];
    float* y = (float*)d_out;

    k1_precompute<<<LEN / 256, 256, 0, stream>>>(
        norm_b, ema_delta, ema_alpha, ema_beta, ema_gamma, ema_omega,
        Wv, bv, Wmx, bmx, Wh, attn_gamma, attn_beta, rot_alpha, rot_beta);

    k2_rowsum<<<LEN, 256, 0, stream>>>(bh);

    kB_output<<<PDIM / 2, 512, 0, stream>>>(x, Wlin, blin, y);
}

// Round 8
// 116.431 us; speedup vs baseline: 1.1489x; 1.0415x over previous
//
#include <hip/hip_runtime.h>
#include <hip/hip_bf16.h>
#include <math.h>

// Shapes: L=2048, B=32, E=1, S=4, D=8, N=8, P=720
#define LEN 2048
#define BDIM 32
#define PDIM 720
#define LROWS 8              // l-rows per block in k2_tiled

// Device-global scratch (NOT d_ws; harness never touches these). Every region
// fully overwritten each call before any read (k1 writes Qv/Kv/u/hx/wsum; k2
// writes hh) => no cross-call state, re-poison-safe. 16B-aligned for float4.
__device__ __attribute__((aligned(16))) float g_Qv[LEN * 8];
__device__ __attribute__((aligned(16))) float g_Kv[LEN * 8];
__device__ __attribute__((aligned(16))) float g_u[LEN];
__device__ __attribute__((aligned(16))) float g_hx[LEN];
__device__ __attribute__((aligned(16))) float g_wsum[LEN];
__device__ __attribute__((aligned(16))) float g_hh[LEN];

__device__ __forceinline__ float sigmoidf_(float x) { return 1.0f / (1.0f + expf(-x)); }
__device__ __forceinline__ float siluf_(float x)    { return x / (1.0f + expf(-x)); }

// ---------------- K1: per-position precompute (E=1 collapse) ----------------
// Proven R3/R5/R7. xn == norm_b[0] (constant c); FFT long-conv replaced by
// closed-form geometric prefix.
__global__ void k1_precompute(
    const float* __restrict__ norm_b,
    const float* __restrict__ ema_delta, const float* __restrict__ ema_alpha,
    const float* __restrict__ ema_beta,  const float* __restrict__ ema_gamma,
    const float* __restrict__ ema_omega,
    const float* __restrict__ Wv, const float* __restrict__ bv,
    const float* __restrict__ Wmx, const float* __restrict__ bmx,
    const float* __restrict__ Wh,
    const float* __restrict__ attn_gamma, const float* __restrict__ attn_beta,
    const float* __restrict__ rot_alpha,  const float* __restrict__ rot_beta)
{
    const int l = blockIdx.x * blockDim.x + threadIdx.x;
    if (l >= LEN) return;

    const float c = norm_b[0];
    const float res_e = c * ema_omega[0];

    float conv = 0.0f;
    #pragma unroll
    for (int n = 0; n < 8; ++n) {
        float p  = sigmoidf_(ema_delta[n]);
        float s  = sigmoidf_(ema_alpha[n]);
        float om = p * s;            // 1-q in (0,1)
        float q  = 1.0f - om;
        float g  = p * ema_beta[n] * ema_gamma[n] * 0.35355339059327373f; // 1/sqrt(8)
        float qp = expf((float)(l + 1) * logf(q));
        conv += g * (1.0f - qp) / om;
    }
    conv *= c;

    const float mx = siluf_(conv + res_e);

    const float u  = sigmoidf_(fmaf(mx, Wmx[0], bmx[0]));
    float z[4];
    #pragma unroll
    for (int s = 0; s < 4; ++s) z[s] = siluf_(fmaf(mx, Wmx[1 + s], bmx[1 + s]));
    float r[8];
    #pragma unroll
    for (int d = 0; d < 8; ++d) r[d] = siluf_(fmaf(mx, Wmx[5 + d], bmx[5 + d]));
    const float hx = fmaf(mx, Wmx[13], bmx[13]);

    float ws = 0.0f;
    #pragma unroll
    for (int d = 0; d < 8; ++d) {
        float v = siluf_(fmaf(c, Wv[d], bv[d]));
        ws += v * r[d] * Wh[d];
    }

    // rotary: half=2, freq={1, exp(-log(1e4)/2)}
    const float f1 = expf(-logf(10000.0f) * 0.5f);
    const float c0 = cosf((float)l),      s0 = sinf((float)l);
    const float th = (float)l * f1;
    const float c1 = cosf(th),            s1 = sinf(th);

    const float ra0 = rot_alpha[0] * c0 - rot_alpha[2] * s0;
    const float ra1 = rot_alpha[1] * c1 - rot_alpha[3] * s1;
    const float ra2 = rot_alpha[2] * c0 + rot_alpha[0] * s0;
    const float ra3 = rot_alpha[3] * c1 + rot_alpha[1] * s1;
    const float rb0 = rot_beta[0] * c0 - rot_beta[2] * s0;
    const float rb1 = rot_beta[1] * c1 - rot_beta[3] * s1;
    const float rb2 = rot_beta[2] * c0 + rot_beta[0] * s0;
    const float rb3 = rot_beta[3] * c1 + rot_beta[1] * s1;

    const float invL = 1.0f / (float)LEN;
    float* q8 = g_Qv + l * 8;
    float* k8 = g_Kv + l * 8;
    #pragma unroll
    for (int s = 0; s < 4; ++s) {
        q8[s] = fmaf(z[s], attn_gamma[s],     attn_beta[s])     * invL;
        k8[s] = fmaf(z[s], attn_gamma[4 + s], attn_beta[4 + s]);
    }
    q8[4] = ra0; q8[5] = ra1; q8[6] = ra2; q8[7] = ra3;
    k8[4] = rb0; k8[5] = rb1; k8[6] = rb2; k8[7] = rb3;

    g_u[l] = u; g_hx[l] = hx; g_wsum[l] = ws;
}

// ---------------- K2: row-tiled attention row-sum ---------------------------
// A[l] = sum_m relu(Qv[l].Kv[m])^2; hh = silu(hx + A*wsum + bh0).
// 256 blocks x 256 thr; block owns l = blk*8..+7. Kv staged ONCE per block
// into LDS transposed kv[d][m] (L2 Kv traffic 128 -> 16 MB). Fill and read
// are both bank = m%32 => conflict-free across a wave.
__global__ void k2_tiled(const float* __restrict__ bh)
{
    __shared__ float kv[8][LEN];          // 64 KB transposed
    __shared__ float red[4][LROWS];

    const int tid   = threadIdx.x;
    const int wave  = tid >> 6;
    const int lane  = tid & 63;
    const int lbase = blockIdx.x * LROWS;

    // stage Kv: thread t handles m = t + k*256; float4 global, scalar LDS
    #pragma unroll
    for (int k = 0; k < 8; ++k) {
        const int m = tid + (k << 8);
        const float4 ka = ((const float4*)g_Kv)[m * 2];
        const float4 kb = ((const float4*)g_Kv)[m * 2 + 1];
        kv[0][m] = ka.x; kv[1][m] = ka.y; kv[2][m] = ka.z; kv[3][m] = ka.w;
        kv[4][m] = kb.x; kv[5][m] = kb.y; kv[6][m] = kb.z; kv[7][m] = kb.w;
    }

    // own-row Q vectors (registers, broadcast loads from L2/L1)
    float q[LROWS][8];
    #pragma unroll
    for (int r = 0; r < LROWS; ++r) {
        const float4 qa = ((const float4*)g_Qv)[(lbase + r) * 2];
        const float4 qb = ((const float4*)g_Qv)[(lbase + r) * 2 + 1];
        q[r][0] = qa.x; q[r][1] = qa.y; q[r][2] = qa.z; q[r][3] = qa.w;
        q[r][4] = qb.x; q[r][5] = qb.y; q[r][6] = qb.z; q[r][7] = qb.w;
    }
    __syncthreads();

    // dot phase: m = tid + k*256, 8 rows per m
    float acc[LROWS] = {0, 0, 0, 0, 0, 0, 0, 0};
    #pragma unroll
    for (int k = 0; k < 8; ++k) {
        const int m = tid + (k << 8);
        float kd[8];
        #pragma unroll
        for (int d = 0; d < 8; ++d) kd[d] = kv[d][m];     // conflict-free b32
        #pragma unroll
        for (int r = 0; r < LROWS; ++r) {
            float dot = q[r][0] * kd[0] + q[r][1] * kd[1] + q[r][2] * kd[2]
                      + q[r][3] * kd[3] + q[r][4] * kd[4] + q[r][5] * kd[5]
                      + q[r][6] * kd[6] + q[r][7] * kd[7];
            dot = fmaxf(dot, 0.0f);
            acc[r] = fmaf(dot, dot, acc[r]);
        }
    }

    // block reduction -> hh
    #pragma unroll
    for (int r = 0; r < LROWS; ++r) {
        #pragma unroll
        for (int off = 32; off; off >>= 1)
            acc[r] += __shfl_down(acc[r], off, 64);
    }
    if (lane == 0) {
        #pragma unroll
        for (int r = 0; r < LROWS; ++r) red[wave][r] = acc[r];
    }
    __syncthreads();
    if (tid < LROWS) {
        const int l = lbase + tid;
        float A = red[0][tid] + red[1][tid] + red[2][tid] + red[3][tid];
        g_hh[l] = siluf_(g_hx[l] + A * g_wsum[l] + bh[0]);
    }
}

// ---------------- KB: fused gate + output projection, 2 p-rows/block --------
// Proven R7. y[b,p] = blin[p] + sum_l (x[b,l] + u[l]*(hh[l]-x[b,l])) * Wlin[p,l]
__global__ void kB_output(
    const float* __restrict__ x,
    const float* __restrict__ Wlin, const float* __restrict__ blin,
    float* __restrict__ y)
{
    const int p0    = blockIdx.x * 2;
    const int tid   = threadIdx.x;
    const int wave  = tid >> 6;          // 0..7
    const int lane  = tid & 63;
    const int bbase = wave * 4;

    const float4* W0 = (const float4*)(Wlin + (size_t)p0 * LEN);
    const float4* W1 = (const float4*)(Wlin + (size_t)(p0 + 1) * LEN);
    const float4* U4 = (const float4*)g_u;
    const float4* H4 = (const float4*)g_hh;

    float acc0[4] = {0, 0, 0, 0};
    float acc1[4] = {0, 0, 0, 0};

    #pragma unroll 2
    for (int k = 0; k < 8; ++k) {
        const int i4 = (k << 6) + lane;   // float4 index along l
        const float4 w0 = W0[i4];
        const float4 w1 = W1[i4];
        const float4 uv = U4[i4];
        const float4 hv = H4[i4];
        float4 xv[4];
        #pragma unroll
        for (int j = 0; j < 4; ++j)
            xv[j] = ((const float4*)(x + (size_t)(bbase + j) * LEN))[i4];

        #pragma unroll
        for (int j = 0; j < 4; ++j) {
            float ox = fmaf(uv.x, hv.x - xv[j].x, xv[j].x);
            float oy = fmaf(uv.y, hv.y - xv[j].y, xv[j].y);
            float oz = fmaf(uv.z, hv.z - xv[j].z, xv[j].z);
            float ow = fmaf(uv.w, hv.w - xv[j].w, xv[j].w);
            acc0[j] += fmaf(ox, w0.x, fmaf(oy, w0.y, fmaf(oz, w0.z, ow * w0.w)));
            acc1[j] += fmaf(ox, w1.x, fmaf(oy, w1.y, fmaf(oz, w1.z, ow * w1.w)));
        }
    }

    #pragma unroll
    for (int j = 0; j < 4; ++j) {
        float v0 = acc0[j], v1 = acc1[j];
        #pragma unroll
        for (int off = 32; off; off >>= 1) {
            v0 += __shfl_down(v0, off, 64);
            v1 += __shfl_down(v1, off, 64);
        }
        if (lane == 0) {
            const size_t row = (size_t)(bbase + j) * PDIM;
            y[row + p0]     = v0 + blin[p0];
            y[row + p0 + 1] = v1 + blin[p0 + 1];
        }
    }
}

// ---------------- launch ----------------------------------------------------
extern "C" void kernel_launch(void* const* d_in, const int* in_sizes, int n_in,
                              void* d_out, int out_size, void* d_ws, size_t ws_size,
                              hipStream_t stream)
{
    const float* x          = (const float*)d_in[0];
    // d_in[1] = norm_w (dead: multiplies exact zero since E=1)
    const float* norm_b     = (const float*)d_in[2];
    const float* ema_delta  = (const float*)d_in[3];
    const float* ema_alpha  = (const float*)d_in[4];
    const float* ema_beta   = (const float*)d_in[5];
    const float* ema_gamma  = (const float*)d_in[6];
    const float* ema_omega  = (const float*)d_in[7];
    const float* Wv         = (const float*)d_in[8];
    const float* bv         = (const float*)d_in[9];
    const float* Wmx        = (const float*)d_in[10];
    const float* bmx        = (const float*)d_in[11];
    const float* Wh         = (const float*)d_in[12];
    const float* bh         = (const float*)d_in[13];
    const float* attn_gamma = (const float*)d_in[14];
    const float* attn_beta  = (const float*)d_in[15];
    const float* rot_alpha  = (const float*)d_in[16];
    const float* rot_beta   = (const float*)d_in[17];
    const float* Wlin       = (const float*)d_in[18];
    const float* blin       = (const float*)d_in[19];
    float* y = (float*)d_out;

    k1_precompute<<<LEN / 256, 256, 0, stream>>>(
        norm_b, ema_delta, ema_alpha, ema_beta, ema_gamma, ema_omega,
        Wv, bv, Wmx, bmx, Wh, attn_gamma, attn_beta, rot_alpha, rot_beta);

    k2_tiled<<<LEN / LROWS, 256, 0, stream>>>(bh);

    kB_output<<<PDIM / 2, 512, 0, stream>>>(x, Wlin, blin, y);
}